// Round 11
// baseline (335.886 us; speedup 1.0000x reference)
//
#include <hip/hip_runtime.h>
#include <hip/hip_bf16.h>

#define O_DIM 4096
#define I_DIM 4096
#define B_DIM 512
#define NQ ((O_DIM * I_DIM) / 4)

typedef short bf16x8 __attribute__((ext_vector_type(8)));
typedef float f32x4 __attribute__((ext_vector_type(4)));

__device__ __forceinline__ unsigned short f2bf(float x) {
    return __builtin_bit_cast(unsigned short, __float2bfloat16(x));
}

// ---------------------------------------------------------------------------
// Proven R1 mask body for one quad (4 elements): f32 fast path, rare f64
// re-resolve at margin < 1e-3 (matches numpy f64 argmax; absmax 0.0459).
// ---------------------------------------------------------------------------
__device__ __forceinline__ void mask_quad(
    const float* wts, const float* pb, const float* pf,
    const float* pp, const float* noise, unsigned short* wm, int q)
{
    float4 b4 = ((const float4*)pb)[q];
    float4 f4 = ((const float4*)pf)[q];
    float4 p4 = ((const float4*)pp)[q];
    float4 w4 = ((const float4*)wts)[q];
    float4 n0 = ((const float4*)noise)[(long)q*3 + 0];
    float4 n1 = ((const float4*)noise)[(long)q*3 + 1];
    float4 n2 = ((const float4*)noise)[(long)q*3 + 2];
    float lb[4] = {b4.x, b4.y, b4.z, b4.w};
    float lf[4] = {f4.x, f4.y, f4.z, f4.w};
    float lp[4] = {p4.x, p4.y, p4.z, p4.w};
    float wv[4] = {w4.x, w4.y, w4.z, w4.w};
    float uu[12] = {n0.x,n0.y,n0.z,n0.w, n1.x,n1.y,n1.z,n1.w, n2.x,n2.y,n2.z,n2.w};
    unsigned short out[4];
    #pragma unroll
    for (int j = 0; j < 4; ++j) {
        float u0 = uu[3*j+0], u1 = uu[3*j+1], u2 = uu[3*j+2];
        float t0 = lb[j] - __logf(-__logf(u0 + 1e-20f) + 1e-20f);
        float t1 = lf[j] - __logf(-__logf(u1 + 1e-20f) + 1e-20f);
        float t2 = lp[j] - __logf(-__logf(u2 + 1e-20f) + 1e-20f);
        int k = 0; float best = t0;
        if (t1 > best) { best = t1; k = 1; }
        if (t2 > best) { best = t2; k = 2; }
        float sec = (k == 0) ? fmaxf(t1, t2)
                  : (k == 1) ? fmaxf(t0, t2) : fmaxf(t0, t1);
        if (best - sec < 1e-3f) {
            double d0 = (double)lb[j] - log(-log((double)u0 + 1e-20) + 1e-20);
            double d1 = (double)lf[j] - log(-log((double)u1 + 1e-20) + 1e-20);
            double d2 = (double)lp[j] - log(-log((double)u2 + 1e-20) + 1e-20);
            k = 0; double db = d0;
            if (d1 > db) { db = d1; k = 1; }
            if (d2 > db) { k = 2; }
        }
        float mw = (k == 0) ? wv[j] : (k == 1) ? -wv[j] : 0.0f;
        out[j] = f2bf(mw);
    }
    ushort4 o4 = {out[0], out[1], out[2], out[3]};
    ((ushort4*)wm)[q] = o4;
}

#define BM 128
#define BN 128
#define BK 64
#define MASK_BLOCKS 256

__global__ void init_flags(int* flags) {
    if (threadIdx.x < 33) flags[threadIdx.x] = 0;
}

// ---------------------------------------------------------------------------
// Fused producer-consumer kernel.
// Blocks [0,256): producers — cvt 2 x-rows -> xflag; mask 16 W-rows
//   (panel-major: panel p=128 rows has producers [8p,8p+8)) -> panel flag.
// Blocks [256,512): gemm workers — 2 tiles (T=g and T=g+256; bn=T>>4,
//   bm=(T>>2)&3, ph=T&3): first tile bn in [0,16) runs while late panels
//   are still being masked; second tile bn in [16,32) just-in-time.
// Sync: producers __threadfence() (all threads) + __syncthreads + release
//   atomicAdd; consumers relaxed spin + s_sleep, then __threadfence().
// All 512 blocks co-resident (64 KB LDS, launch_bounds(256,2)) ->
// producers always progress; consumers only wait on producers: no cycles.
// GEMM body identical to the proven R9/R10 kernel.
// ---------------------------------------------------------------------------
__global__ __launch_bounds__(256, 2) void fused_kernel(
    const float* x, const float* wts,
    const float* pb, const float* pf, const float* pp, const float* noise,
    unsigned short* wm, unsigned short* xb,
    float* C0, float* P, int* flags)
{
    __shared__ unsigned short Asm[2][BM * BK];
    __shared__ unsigned short Bsm[2][BN * BK];
    const int K = I_DIM;
    int tid = threadIdx.x;
    int b = blockIdx.x;

    if (b < MASK_BLOCKS) {
        // ---- cvt: x rows [2b, 2b+2) -> xb (bf16) ----
        const float4* xs = (const float4*)x + (size_t)b * 2048;
        ushort4* xd = (ushort4*)xb + (size_t)b * 2048;
        #pragma unroll
        for (int i = 0; i < 8; ++i) {
            float4 v = xs[i * 256 + tid];
            ushort4 o = {f2bf(v.x), f2bf(v.y), f2bf(v.z), f2bf(v.w)};
            xd[i * 256 + tid] = o;
        }
        __threadfence();
        __syncthreads();
        if (tid == 0)
            __hip_atomic_fetch_add(&flags[32], 1, __ATOMIC_RELEASE,
                                   __HIP_MEMORY_SCOPE_AGENT);
        // ---- mask: W rows [16b, 16b+16) = quads [b*16384, +16384) ----
        int qbase = b * 16384;
        #pragma unroll 1
        for (int i = 0; i < 64; ++i)
            mask_quad(wts, pb, pf, pp, noise, wm, qbase + i * 256 + tid);
        __threadfence();
        __syncthreads();
        if (tid == 0)
            __hip_atomic_fetch_add(&flags[b >> 3], 1, __ATOMIC_RELEASE,
                                   __HIP_MEMORY_SCOPE_AGENT);
        return;
    }

    // ---- gemm worker ----
    int g = b - MASK_BLOCKS;
    int w = tid >> 6, l = tid & 63;
    int wr = w >> 1, wc = w & 1;
    int lrow = l & 15, lhi = l >> 4, swz = l & 7;
    int srow = l >> 3;
    int schunk = (l & 7) ^ srow;

    for (int rep = 0; rep < 2; ++rep) {
        int T  = g + rep * 256;
        int bn = T >> 4, bm = (T >> 2) & 3, ph = T & 3;
        int bm0 = bm * BM, bn0 = bn * BN;
        int kbeg = ph * (K / 4);
        float* Ct = (ph == 0) ? C0 : &P[(size_t)(ph - 1) * B_DIM * O_DIM];

        if (tid == 0) {
            while (__hip_atomic_load(&flags[32], __ATOMIC_RELAXED,
                                     __HIP_MEMORY_SCOPE_AGENT) < MASK_BLOCKS)
                __builtin_amdgcn_s_sleep(8);
            while (__hip_atomic_load(&flags[bn], __ATOMIC_RELAXED,
                                     __HIP_MEMORY_SCOPE_AGENT) < 8)
                __builtin_amdgcn_s_sleep(8);
        }
        __syncthreads();
        __threadfence();   // acquire: invalidate stale lines before wm/xb reads

        f32x4 acc[4][4] = {};

#define STAGE(buf, k0)                                                         \
    {                                                                          \
        _Pragma("unroll")                                                      \
        for (int j = 0; j < 4; ++j) {                                          \
            int rr = j * 32 + w * 8 + srow;                                    \
            const unsigned short* sa = &xb[(size_t)(bm0 + rr) * K + (k0) + schunk * 8]; \
            const unsigned short* sb = &wm[(size_t)(bn0 + rr) * K + (k0) + schunk * 8]; \
            __builtin_amdgcn_global_load_lds(                                  \
                (const __attribute__((address_space(1))) void*)sa,             \
                (__attribute__((address_space(3))) void*)&Asm[buf][(j * 32 + w * 8) * BK], \
                16, 0, 0);                                                     \
            __builtin_amdgcn_global_load_lds(                                  \
                (const __attribute__((address_space(1))) void*)sb,             \
                (__attribute__((address_space(3))) void*)&Bsm[buf][(j * 32 + w * 8) * BK], \
                16, 0, 0);                                                     \
        }                                                                      \
    }

        STAGE(0, kbeg);
        __syncthreads();

        for (int t = 0; t < 16; ++t) {
            int cur = t & 1;
            if (t + 1 < 16) STAGE(cur ^ 1, kbeg + (t + 1) * BK);

            #pragma unroll
            for (int kk = 0; kk < 2; ++kk) {
                bf16x8 a[4], bfr[4];
                #pragma unroll
                for (int m = 0; m < 4; ++m)
                    a[m] = *(const bf16x8*)&Asm[cur][(wr * 64 + m * 16 + lrow) * BK +
                                                     (((kk * 4 + lhi) ^ swz) * 8)];
                #pragma unroll
                for (int n = 0; n < 4; ++n)
                    bfr[n] = *(const bf16x8*)&Bsm[cur][(wc * 64 + n * 16 + lrow) * BK +
                                                       (((kk * 4 + lhi) ^ swz) * 8)];
                #pragma unroll
                for (int m = 0; m < 4; ++m)
                    #pragma unroll
                    for (int n = 0; n < 4; ++n)
                        acc[m][n] = __builtin_amdgcn_mfma_f32_16x16x32_bf16(
                            a[m], bfr[n], acc[m][n], 0, 0, 0);
            }
            __syncthreads();
        }
#undef STAGE

        int crow0 = bm0 + wr * 64 + lhi * 4;
        #pragma unroll
        for (int n = 0; n < 4; ++n) {
            int col = bn0 + wc * 64 + n * 16 + lrow;
            #pragma unroll
            for (int m = 0; m < 4; ++m)
                #pragma unroll
                for (int r = 0; r < 4; ++r)
                    Ct[(size_t)(crow0 + m * 16 + r) * O_DIM + col] = acc[m][n][r];
        }
        __syncthreads();   // LDS safe for next rep
    }
}

// ---------------------------------------------------------------------------
// Reduce: out = out(phase0) + sum P[p] + bias.
// ---------------------------------------------------------------------------
__global__ __launch_bounds__(256) void reduce_kernel(
    float* __restrict__ out, const float* __restrict__ P,
    const float* __restrict__ bias, int nphase)
{
    const int total4 = (B_DIM * O_DIM) / 4;
    const int BO4 = B_DIM * O_DIM / 4;
    int stride = gridDim.x * blockDim.x;
    for (int q = blockIdx.x * blockDim.x + threadIdx.x; q < total4; q += stride) {
        float4 v = ((const float4*)out)[q];
        float4 b = ((const float4*)bias)[q & (O_DIM / 4 - 1)];
        for (int p = 0; p + 1 < nphase; ++p) {
            float4 w = ((const float4*)P)[(size_t)p * BO4 + q];
            v.x += w.x; v.y += w.y; v.z += w.z; v.w += w.w;
        }
        v.x += b.x; v.y += b.y; v.z += b.z; v.w += b.w;
        ((float4*)out)[q] = v;
    }
}

// ---------------------------------------------------------------------------
// Fallback serial path (proven R10): mask / cvt / gemm kernels.
// ---------------------------------------------------------------------------
__global__ __launch_bounds__(256) void mask_kernel(
    const float* __restrict__ wts,
    const float* __restrict__ pb, const float* __restrict__ pf,
    const float* __restrict__ pp, const float* __restrict__ noise,
    unsigned short* __restrict__ wm)
{
    const int total4 = NQ;
    int stride = gridDim.x * blockDim.x;
    for (int q = blockIdx.x * blockDim.x + threadIdx.x; q < total4; q += stride)
        mask_quad(wts, pb, pf, pp, noise, wm, q);
}

__global__ __launch_bounds__(256) void cvt_kernel(
    const float* __restrict__ x, unsigned short* __restrict__ xb)
{
    const int total4 = (B_DIM * I_DIM) / 4;
    int stride = gridDim.x * blockDim.x;
    for (int q = blockIdx.x * blockDim.x + threadIdx.x; q < total4; q += stride) {
        float4 v = ((const float4*)x)[q];
        ushort4 o = {f2bf(v.x), f2bf(v.y), f2bf(v.z), f2bf(v.w)};
        ((ushort4*)xb)[q] = o;
    }
}

#define NTILES ((B_DIM / BM) * (O_DIM / BN))

__global__ __launch_bounds__(256, 2) void gemm_kernel(
    const unsigned short* __restrict__ A,
    const unsigned short* __restrict__ Bw,
    float* __restrict__ C0, float* __restrict__ P, int nphase, int lsp)
{
    __shared__ unsigned short Asm[2][BM * BK];
    __shared__ unsigned short Bsm[2][BN * BK];
    const int K = I_DIM;

    int bid = blockIdx.x;
    int c   = bid & 7;
    int bm  = (bid >> 3) & 3;
    int i   = bid >> 5;
    int kphase = c & (nphase - 1);
    int bn  = ((c >> lsp) << (2 + lsp)) + i;

    int klen   = K / nphase;
    int kbeg   = kphase * klen;
    int nt     = klen / BK;
    float* __restrict__ Ct = (kphase == 0) ? C0
                           : &P[(size_t)(kphase - 1) * B_DIM * O_DIM];

    int tid = threadIdx.x;
    int w = tid >> 6, l = tid & 63;
    int bm0 = bm * BM, bn0 = bn * BN;
    int wr = w >> 1, wc = w & 1;
    int lrow = l & 15, lhi = l >> 4, swz = l & 7;
    int srow = l >> 3;
    int schunk = (l & 7) ^ srow;

    f32x4 acc[4][4] = {};

#define STAGE(buf, k0)                                                         \
    {                                                                          \
        _Pragma("unroll")                                                      \
        for (int j = 0; j < 4; ++j) {                                          \
            int rr = j * 32 + w * 8 + srow;                                    \
            const unsigned short* sa = &A[(size_t)(bm0 + rr) * K + (k0) + schunk * 8];  \
            const unsigned short* sb = &Bw[(size_t)(bn0 + rr) * K + (k0) + schunk * 8]; \
            __builtin_amdgcn_global_load_lds(                                  \
                (const __attribute__((address_space(1))) void*)sa,             \
                (__attribute__((address_space(3))) void*)&Asm[buf][(j * 32 + w * 8) * BK], \
                16, 0, 0);                                                     \
            __builtin_amdgcn_global_load_lds(                                  \
                (const __attribute__((address_space(1))) void*)sb,             \
                (__attribute__((address_space(3))) void*)&Bsm[buf][(j * 32 + w * 8) * BK], \
                16, 0, 0);                                                     \
        }                                                                      \
    }

    STAGE(0, kbeg);
    __syncthreads();

    for (int t = 0; t < nt; ++t) {
        int cur = t & 1;
        if (t + 1 < nt) STAGE(cur ^ 1, kbeg + (t + 1) * BK);

        #pragma unroll
        for (int kk = 0; kk < 2; ++kk) {
            bf16x8 a[4], bfr[4];
            #pragma unroll
            for (int m = 0; m < 4; ++m)
                a[m] = *(const bf16x8*)&Asm[cur][(wr * 64 + m * 16 + lrow) * BK +
                                                 (((kk * 4 + lhi) ^ swz) * 8)];
            #pragma unroll
            for (int n = 0; n < 4; ++n)
                bfr[n] = *(const bf16x8*)&Bsm[cur][(wc * 64 + n * 16 + lrow) * BK +
                                                   (((kk * 4 + lhi) ^ swz) * 8)];
            #pragma unroll
            for (int m = 0; m < 4; ++m)
                #pragma unroll
                for (int n = 0; n < 4; ++n)
                    acc[m][n] = __builtin_amdgcn_mfma_f32_16x16x32_bf16(
                        a[m], bfr[n], acc[m][n], 0, 0, 0);
        }
        __syncthreads();
    }
#undef STAGE

    int crow0 = bm0 + wr * 64 + lhi * 4;
    #pragma unroll
    for (int n = 0; n < 4; ++n) {
        int col = bn0 + wc * 64 + n * 16 + lrow;
        #pragma unroll
        for (int m = 0; m < 4; ++m)
            #pragma unroll
            for (int r = 0; r < 4; ++r)
                Ct[(size_t)(crow0 + m * 16 + r) * O_DIM + col] = acc[m][n][r];
    }
}

extern "C" void kernel_launch(void* const* d_in, const int* in_sizes, int n_in,
                              void* d_out, int out_size, void* d_ws, size_t ws_size,
                              hipStream_t stream) {
    const float* x    = (const float*)d_in[0];
    const float* wts  = (const float*)d_in[1];
    const float* bias = (const float*)d_in[2];
    const float* pb   = (const float*)d_in[3];
    const float* pf   = (const float*)d_in[4];
    const float* pp   = (const float*)d_in[5];
    const float* un   = (const float*)d_in[6];
    float* out = (float*)d_out;

    unsigned short* wm = (unsigned short*)d_ws;              // 32 MB bf16 masked W
    unsigned short* xb = wm + (size_t)O_DIM * I_DIM;         // 4 MB bf16 x
    size_t p_off = ((size_t)O_DIM * I_DIM + (size_t)B_DIM * I_DIM) * 2;
    float* P = (float*)((char*)d_ws + p_off);                // 3x 8MB partials
    const size_t BO = (size_t)B_DIM * O_DIM * 4;
    size_t flags_off = p_off + 3 * BO;
    int* flags = (int*)((char*)d_ws + flags_off);

    if (ws_size >= flags_off + 256) {
        // fused overlapped path
        init_flags<<<1, 64, 0, stream>>>(flags);
        fused_kernel<<<512, 256, 0, stream>>>(x, wts, pb, pf, pp, un,
                                              wm, xb, out, P, flags);
        reduce_kernel<<<2048, 256, 0, stream>>>(out, P, bias, 4);
    } else {
        // proven serial fallback
        int nphase = (ws_size >= p_off + 3 * BO) ? 4
                   : (ws_size >= p_off + 1 * BO) ? 2 : 1;
        int lsp = (nphase == 4) ? 2 : (nphase == 2) ? 1 : 0;
        mask_kernel<<<2048, 256, 0, stream>>>(wts, pb, pf, pp, un, wm);
        cvt_kernel<<<512, 256, 0, stream>>>(x, xb);
        gemm_kernel<<<dim3(NTILES * nphase), 256, 0, stream>>>(xb, wm, out, P, nphase, lsp);
        reduce_kernel<<<2048, 256, 0, stream>>>(out, P, bias, nphase);
    }
}

// Round 12
// 166.082 us; speedup vs baseline: 2.0224x; 2.0224x over previous
//
#include <hip/hip_runtime.h>
#include <hip/hip_bf16.h>

#define O_DIM 4096
#define I_DIM 4096
#define B_DIM 512
#define NQ ((O_DIM * I_DIM) / 4)

typedef short bf16x8 __attribute__((ext_vector_type(8)));
typedef float f32x4 __attribute__((ext_vector_type(4)));

__device__ __forceinline__ unsigned short f2bf(float x) {
    return __builtin_bit_cast(unsigned short, __float2bfloat16(x));
}

// ---------------------------------------------------------------------------
// Mask kernel — R1-exact (timed ~103 us = 4.7 TB/s logical, within ~4% of
// the measured multi-stream streaming ceiling (m146: 4.89 TB/s). DONE.
// rocprof rows for this kernel are cold-L3 replay artifacts — ignore).
// ---------------------------------------------------------------------------
__global__ __launch_bounds__(256) void mask_kernel(
    const float* __restrict__ wts,
    const float* __restrict__ pb, const float* __restrict__ pf,
    const float* __restrict__ pp, const float* __restrict__ noise,
    unsigned short* __restrict__ wm)
{
    const int total4 = NQ;
    int stride = gridDim.x * blockDim.x;
    for (int q = blockIdx.x * blockDim.x + threadIdx.x; q < total4; q += stride) {
        float4 b4 = ((const float4*)pb)[q];
        float4 f4 = ((const float4*)pf)[q];
        float4 p4 = ((const float4*)pp)[q];
        float4 w4 = ((const float4*)wts)[q];
        float4 n0 = ((const float4*)noise)[(long)q*3 + 0];
        float4 n1 = ((const float4*)noise)[(long)q*3 + 1];
        float4 n2 = ((const float4*)noise)[(long)q*3 + 2];
        float lb[4] = {b4.x, b4.y, b4.z, b4.w};
        float lf[4] = {f4.x, f4.y, f4.z, f4.w};
        float lp[4] = {p4.x, p4.y, p4.z, p4.w};
        float wv[4] = {w4.x, w4.y, w4.z, w4.w};
        float uu[12] = {n0.x,n0.y,n0.z,n0.w, n1.x,n1.y,n1.z,n1.w, n2.x,n2.y,n2.z,n2.w};
        unsigned short out[4];
        #pragma unroll
        for (int j = 0; j < 4; ++j) {
            float u0 = uu[3*j+0], u1 = uu[3*j+1], u2 = uu[3*j+2];
            float t0 = lb[j] - __logf(-__logf(u0 + 1e-20f) + 1e-20f);
            float t1 = lf[j] - __logf(-__logf(u1 + 1e-20f) + 1e-20f);
            float t2 = lp[j] - __logf(-__logf(u2 + 1e-20f) + 1e-20f);
            int k = 0; float best = t0;
            if (t1 > best) { best = t1; k = 1; }
            if (t2 > best) { best = t2; k = 2; }
            float sec = (k == 0) ? fmaxf(t1, t2)
                      : (k == 1) ? fmaxf(t0, t2) : fmaxf(t0, t1);
            if (best - sec < 1e-3f) {  // near-tie: resolve in f64 (rare)
                double d0 = (double)lb[j] - log(-log((double)u0 + 1e-20) + 1e-20);
                double d1 = (double)lf[j] - log(-log((double)u1 + 1e-20) + 1e-20);
                double d2 = (double)lp[j] - log(-log((double)u2 + 1e-20) + 1e-20);
                k = 0; double db = d0;
                if (d1 > db) { db = d1; k = 1; }
                if (d2 > db) { k = 2; }
            }
            float mw = (k == 0) ? wv[j] : (k == 1) ? -wv[j] : 0.0f;
            out[j] = f2bf(mw);
        }
        ushort4 o4 = {out[0], out[1], out[2], out[3]};
        ((ushort4*)wm)[q] = o4;
    }
}

// ---------------------------------------------------------------------------
// x (f32) -> bf16
// ---------------------------------------------------------------------------
__global__ __launch_bounds__(256) void cvt_kernel(
    const float* __restrict__ x, unsigned short* __restrict__ xb)
{
    const int total4 = (B_DIM * I_DIM) / 4;
    int stride = gridDim.x * blockDim.x;
    for (int q = blockIdx.x * blockDim.x + threadIdx.x; q < total4; q += stride) {
        float4 v = ((const float4*)x)[q];
        ushort4 o = {f2bf(v.x), f2bf(v.y), f2bf(v.z), f2bf(v.w)};
        ((ushort4*)xb)[q] = o;
    }
}

// ---------------------------------------------------------------------------
// GEMM — R7-proven 64x64 kernel with a 3-buffer counted-vmcnt pipeline (T4).
// Fragment layout, XOR-swizzle, decode, epilogue identical to R7 (passed at
// 149.7us). Only the K-loop schedule changes:
//   - 3 LDS buffers (48 KB -> 3 blocks/CU via __launch_bounds__(256,3))
//   - raw s_barrier instead of __syncthreads (no forced vmcnt(0) drain)
//   - per-wave s_waitcnt vmcnt(4): each wave issues exactly 4 gload_lds per
//     STAGE; vmcnt(4) before the barrier => this wave's stage-t portion
//     retired while stage-(t+1)'s 4 loads stay in flight ACROSS the barrier.
//     Every wave does the same wait, and the barrier then guarantees all
//     portions of stage-t are complete. Buffer reuse: STAGE(t+2) writes
//     buf[(t+2)%3] = buf[(t-1)%3], whose readers all passed the iter-t
//     barrier. Final iter waits vmcnt(0).
// ---------------------------------------------------------------------------
#define BM 64
#define BN 64
#define BK 64

__global__ __launch_bounds__(256, 3) void gemm_kernel(
    const unsigned short* __restrict__ A,   // xb [512][4096] bf16
    const unsigned short* __restrict__ Bw,  // wm [4096][4096] bf16
    float* __restrict__ C0, float* __restrict__ C1, int nphase)
{
    __shared__ unsigned short Asm[3][BM * BK];  // 3 x 8 KB
    __shared__ unsigned short Bsm[3][BN * BK];  // 3 x 8 KB
    const int K = I_DIM;

    int idx = blockIdx.x;
    int kphase = (nphase == 2) ? (idx & 1) : 0;
    int tb     = (nphase == 2) ? (idx >> 1) : idx;
    int kbeg   = kphase * (K / nphase);
    int nt     = (K / nphase) / BK;
    float* __restrict__ Ct = kphase ? C1 : C0;

    int tid = threadIdx.x;
    int w = tid >> 6, l = tid & 63;
    int bm0 = (tb >> 6) * BM;
    int bn0 = (tb & 63) * BN;
    int wr = w >> 1, wc = w & 1;
    int lrow = l & 15, lhi = l >> 4, swz = l & 7;

    int srow = l >> 3;                    // 0..7
    int schunk = (l & 7) ^ srow;          // inverse-swizzled source chunk

    f32x4 acc[2][2] = {};

#define STAGE(buf, k0)                                                         \
    {                                                                          \
        _Pragma("unroll")                                                      \
        for (int j = 0; j < 2; ++j) {                                          \
            int rr = j * 32 + w * 8 + srow;                                    \
            const unsigned short* sa = &A[(size_t)(bm0 + rr) * K + (k0) + schunk * 8];  \
            const unsigned short* sb = &Bw[(size_t)(bn0 + rr) * K + (k0) + schunk * 8]; \
            __builtin_amdgcn_global_load_lds(                                  \
                (const __attribute__((address_space(1))) void*)sa,             \
                (__attribute__((address_space(3))) void*)&Asm[buf][(j * 32 + w * 8) * BK], \
                16, 0, 0);                                                     \
            __builtin_amdgcn_global_load_lds(                                  \
                (const __attribute__((address_space(1))) void*)sb,             \
                (__attribute__((address_space(3))) void*)&Bsm[buf][(j * 32 + w * 8) * BK], \
                16, 0, 0);                                                     \
        }                                                                      \
    }

    STAGE(0, kbeg);
    STAGE(1, kbeg + BK);

    int cur = 0;                           // t % 3
    for (int t = 0; t < nt; ++t) {
        if (t + 1 < nt) {
            asm volatile("s_waitcnt vmcnt(4)" ::: "memory");
        } else {
            asm volatile("s_waitcnt vmcnt(0)" ::: "memory");
        }
        __builtin_amdgcn_sched_barrier(0);
        __builtin_amdgcn_s_barrier();

        if (t + 2 < nt) {
            int nb = cur + 2; if (nb >= 3) nb -= 3;
            STAGE(nb, kbeg + (t + 2) * BK);
        }

        bf16x8 a[2][2], b[2][2];
        #pragma unroll
        for (int kk = 0; kk < 2; ++kk) {
            #pragma unroll
            for (int m = 0; m < 2; ++m)
                a[kk][m] = *(const bf16x8*)&Asm[cur][(wr * 32 + m * 16 + lrow) * BK +
                                                     (((kk * 4 + lhi) ^ swz) * 8)];
            #pragma unroll
            for (int n = 0; n < 2; ++n)
                b[kk][n] = *(const bf16x8*)&Bsm[cur][(wc * 32 + n * 16 + lrow) * BK +
                                                     (((kk * 4 + lhi) ^ swz) * 8)];
        }
        #pragma unroll
        for (int kk = 0; kk < 2; ++kk)
            #pragma unroll
            for (int m = 0; m < 2; ++m)
                #pragma unroll
                for (int n = 0; n < 2; ++n)
                    acc[m][n] = __builtin_amdgcn_mfma_f32_16x16x32_bf16(
                        a[kk][m], b[kk][n], acc[m][n], 0, 0, 0);

        ++cur; if (cur >= 3) cur -= 3;
    }
#undef STAGE

    int crow0 = bm0 + wr * 32 + lhi * 4;
    #pragma unroll
    for (int n = 0; n < 2; ++n) {
        int col = bn0 + wc * 32 + n * 16 + lrow;
        #pragma unroll
        for (int m = 0; m < 2; ++m)
            #pragma unroll
            for (int r = 0; r < 4; ++r)
                Ct[(size_t)(crow0 + m * 16 + r) * O_DIM + col] = acc[m][n][r];
    }
}

// ---------------------------------------------------------------------------
// Reduce: out = out(partial0) [+ p1] + bias.
// ---------------------------------------------------------------------------
__global__ __launch_bounds__(256) void reduce_kernel(
    float* __restrict__ out, const float* __restrict__ p1,
    const float* __restrict__ bias, int nphase)
{
    const int total4 = (B_DIM * O_DIM) / 4;
    int stride = gridDim.x * blockDim.x;
    for (int q = blockIdx.x * blockDim.x + threadIdx.x; q < total4; q += stride) {
        float4 v = ((const float4*)out)[q];
        float4 b = ((const float4*)bias)[q & (O_DIM / 4 - 1)];
        if (nphase == 2) {
            float4 w = ((const float4*)p1)[q];
            v.x += w.x; v.y += w.y; v.z += w.z; v.w += w.w;
        }
        v.x += b.x; v.y += b.y; v.z += b.z; v.w += b.w;
        ((float4*)out)[q] = v;
    }
}

extern "C" void kernel_launch(void* const* d_in, const int* in_sizes, int n_in,
                              void* d_out, int out_size, void* d_ws, size_t ws_size,
                              hipStream_t stream) {
    const float* x    = (const float*)d_in[0];
    const float* wts  = (const float*)d_in[1];
    const float* bias = (const float*)d_in[2];
    const float* pb   = (const float*)d_in[3];
    const float* pf   = (const float*)d_in[4];
    const float* pp   = (const float*)d_in[5];
    const float* un   = (const float*)d_in[6];
    float* out = (float*)d_out;

    unsigned short* wm = (unsigned short*)d_ws;              // 32 MB bf16 masked W
    unsigned short* xb = wm + (size_t)O_DIM * I_DIM;         // 4 MB bf16 x
    size_t p_off = ((size_t)O_DIM * I_DIM + (size_t)B_DIM * I_DIM) * 2;
    float* p1 = (float*)((char*)d_ws + p_off);               // 8 MB f32 partial

    int nphase = (ws_size >= p_off + (size_t)B_DIM * O_DIM * 4) ? 2 : 1;

    mask_kernel<<<2048, 256, 0, stream>>>(wts, pb, pf, pp, un, wm);
    cvt_kernel<<<512, 256, 0, stream>>>(x, xb);
    gemm_kernel<<<dim3(512 * nphase), 256, 0, stream>>>(xb, wm, out, p1, nphase);
    reduce_kernel<<<2048, 256, 0, stream>>>(out, p1, bias, nphase);
}

// Round 13
// 150.011 us; speedup vs baseline: 2.2391x; 1.1071x over previous
//
#include <hip/hip_runtime.h>
#include <hip/hip_bf16.h>

#define O_DIM 4096
#define I_DIM 4096
#define B_DIM 512

typedef short bf16x8 __attribute__((ext_vector_type(8)));
typedef float f32x4 __attribute__((ext_vector_type(4)));

__device__ __forceinline__ unsigned short f2bf(float x) {
    return __builtin_bit_cast(unsigned short, __float2bfloat16(x));
}

// ---------------------------------------------------------------------------
// Mask kernel — R1-exact. 480 MB at ~4.7 TB/s logical ≈ 103 us, within ~4%
// of the best measured multi-stream streaming rate (m146: 4.89 TB/s).
// Six structural variants failed to beat it. DONE.
// ---------------------------------------------------------------------------
__global__ __launch_bounds__(256) void mask_kernel(
    const float* __restrict__ wts,
    const float* __restrict__ pb, const float* __restrict__ pf,
    const float* __restrict__ pp, const float* __restrict__ noise,
    unsigned short* __restrict__ wm)
{
    const int total4 = (O_DIM * I_DIM) / 4;
    int stride = gridDim.x * blockDim.x;
    for (int q = blockIdx.x * blockDim.x + threadIdx.x; q < total4; q += stride) {
        float4 b4 = ((const float4*)pb)[q];
        float4 f4 = ((const float4*)pf)[q];
        float4 p4 = ((const float4*)pp)[q];
        float4 w4 = ((const float4*)wts)[q];
        float4 n0 = ((const float4*)noise)[(long)q*3 + 0];
        float4 n1 = ((const float4*)noise)[(long)q*3 + 1];
        float4 n2 = ((const float4*)noise)[(long)q*3 + 2];
        float lb[4] = {b4.x, b4.y, b4.z, b4.w};
        float lf[4] = {f4.x, f4.y, f4.z, f4.w};
        float lp[4] = {p4.x, p4.y, p4.z, p4.w};
        float wv[4] = {w4.x, w4.y, w4.z, w4.w};
        float uu[12] = {n0.x,n0.y,n0.z,n0.w, n1.x,n1.y,n1.z,n1.w, n2.x,n2.y,n2.z,n2.w};
        unsigned short out[4];
        #pragma unroll
        for (int j = 0; j < 4; ++j) {
            float u0 = uu[3*j+0], u1 = uu[3*j+1], u2 = uu[3*j+2];
            float t0 = lb[j] - __logf(-__logf(u0 + 1e-20f) + 1e-20f);
            float t1 = lf[j] - __logf(-__logf(u1 + 1e-20f) + 1e-20f);
            float t2 = lp[j] - __logf(-__logf(u2 + 1e-20f) + 1e-20f);
            int k = 0; float best = t0;
            if (t1 > best) { best = t1; k = 1; }
            if (t2 > best) { best = t2; k = 2; }
            float sec = (k == 0) ? fmaxf(t1, t2)
                      : (k == 1) ? fmaxf(t0, t2) : fmaxf(t0, t1);
            if (best - sec < 1e-3f) {  // near-tie: resolve in f64 (rare)
                double d0 = (double)lb[j] - log(-log((double)u0 + 1e-20) + 1e-20);
                double d1 = (double)lf[j] - log(-log((double)u1 + 1e-20) + 1e-20);
                double d2 = (double)lp[j] - log(-log((double)u2 + 1e-20) + 1e-20);
                k = 0; double db = d0;
                if (d1 > db) { db = d1; k = 1; }
                if (d2 > db) { k = 2; }
            }
            float mw = (k == 0) ? wv[j] : (k == 1) ? -wv[j] : 0.0f;
            out[j] = f2bf(mw);
        }
        ushort4 o4 = {out[0], out[1], out[2], out[3]};
        ((ushort4*)wm)[q] = o4;
    }
}

// ---------------------------------------------------------------------------
// x (f32) -> bf16
// ---------------------------------------------------------------------------
__global__ __launch_bounds__(256) void cvt_kernel(
    const float* __restrict__ x, unsigned short* __restrict__ xb)
{
    const int total4 = (B_DIM * I_DIM) / 4;
    int stride = gridDim.x * blockDim.x;
    for (int q = blockIdx.x * blockDim.x + threadIdx.x; q < total4; q += stride) {
        float4 v = ((const float4*)x)[q];
        ushort4 o = {f2bf(v.x), f2bf(v.y), f2bf(v.z), f2bf(v.w)};
        ((ushort4*)xb)[q] = o;
    }
}

// ---------------------------------------------------------------------------
// GEMM — R7-proven config (best measured: total 149.7 us, gemm ~40 us).
// BM=BN=64, BK=64, 4 waves (2x2), double-buffered LDS via global_load_lds
// width=16, XOR-swizzle chunk^=(row&7) on global source + ds_read,
// single-dispatch split-K=2 (1024 blocks = 4/CU co-resident).
// Schedule surgery beyond this (3-buf counted vmcnt, 128^2 tile, XCD
// swizzle) measured null-to-negative on this 2-phase structure.
// ---------------------------------------------------------------------------
#define BM 64
#define BN 64
#define BK 64

__global__ __launch_bounds__(256, 2) void gemm_kernel(
    const unsigned short* __restrict__ A,   // xb [512][4096] bf16
    const unsigned short* __restrict__ Bw,  // wm [4096][4096] bf16
    float* __restrict__ C0, float* __restrict__ C1, int nphase)
{
    __shared__ unsigned short Asm[2][BM * BK];
    __shared__ unsigned short Bsm[2][BN * BK];
    const int K = I_DIM;

    int idx = blockIdx.x;
    int kphase = (nphase == 2) ? (idx & 1) : 0;
    int tb     = (nphase == 2) ? (idx >> 1) : idx;
    int kbeg   = kphase * (K / nphase);
    int nt     = (K / nphase) / BK;
    float* __restrict__ Ct = kphase ? C1 : C0;

    int tid = threadIdx.x;
    int w = tid >> 6, l = tid & 63;
    int bm0 = (tb >> 6) * BM;
    int bn0 = (tb & 63) * BN;
    int wr = w >> 1, wc = w & 1;
    int lrow = l & 15, lhi = l >> 4, swz = l & 7;

    int srow = l >> 3;
    int schunk = (l & 7) ^ srow;

    f32x4 acc[2][2] = {};

#define STAGE(buf, k0)                                                         \
    {                                                                          \
        _Pragma("unroll")                                                      \
        for (int j = 0; j < 2; ++j) {                                          \
            int rr = j * 32 + w * 8 + srow;                                    \
            const unsigned short* sa = &A[(size_t)(bm0 + rr) * K + (k0) + schunk * 8];  \
            const unsigned short* sb = &Bw[(size_t)(bn0 + rr) * K + (k0) + schunk * 8]; \
            __builtin_amdgcn_global_load_lds(                                  \
                (const __attribute__((address_space(1))) void*)sa,             \
                (__attribute__((address_space(3))) void*)&Asm[buf][(j * 32 + w * 8) * BK], \
                16, 0, 0);                                                     \
            __builtin_amdgcn_global_load_lds(                                  \
                (const __attribute__((address_space(1))) void*)sb,             \
                (__attribute__((address_space(3))) void*)&Bsm[buf][(j * 32 + w * 8) * BK], \
                16, 0, 0);                                                     \
        }                                                                      \
    }

    STAGE(0, kbeg);
    __syncthreads();

    for (int t = 0; t < nt; ++t) {
        int cur = t & 1;
        if (t + 1 < nt) STAGE(cur ^ 1, kbeg + (t + 1) * BK);

        bf16x8 a[2][2], b[2][2];
        #pragma unroll
        for (int kk = 0; kk < 2; ++kk) {
            #pragma unroll
            for (int m = 0; m < 2; ++m)
                a[kk][m] = *(const bf16x8*)&Asm[cur][(wr * 32 + m * 16 + lrow) * BK +
                                                     (((kk * 4 + lhi) ^ swz) * 8)];
            #pragma unroll
            for (int n = 0; n < 2; ++n)
                b[kk][n] = *(const bf16x8*)&Bsm[cur][(wc * 32 + n * 16 + lrow) * BK +
                                                     (((kk * 4 + lhi) ^ swz) * 8)];
        }
        #pragma unroll
        for (int kk = 0; kk < 2; ++kk)
            #pragma unroll
            for (int m = 0; m < 2; ++m)
                #pragma unroll
                for (int n = 0; n < 2; ++n)
                    acc[m][n] = __builtin_amdgcn_mfma_f32_16x16x32_bf16(
                        a[kk][m], b[kk][n], acc[m][n], 0, 0, 0);

        __syncthreads();
    }
#undef STAGE

    int crow0 = bm0 + wr * 32 + lhi * 4;
    #pragma unroll
    for (int n = 0; n < 2; ++n) {
        int col = bn0 + wc * 32 + n * 16 + lrow;
        #pragma unroll
        for (int m = 0; m < 2; ++m)
            #pragma unroll
            for (int r = 0; r < 4; ++r)
                Ct[(size_t)(crow0 + m * 16 + r) * O_DIM + col] = acc[m][n][r];
    }
}

// ---------------------------------------------------------------------------
// Reduce: out = out(partial0) [+ p1] + bias.
// ---------------------------------------------------------------------------
__global__ __launch_bounds__(256) void reduce_kernel(
    float* __restrict__ out, const float* __restrict__ p1,
    const float* __restrict__ bias, int nphase)
{
    const int total4 = (B_DIM * O_DIM) / 4;
    int stride = gridDim.x * blockDim.x;
    for (int q = blockIdx.x * blockDim.x + threadIdx.x; q < total4; q += stride) {
        float4 v = ((const float4*)out)[q];
        float4 b = ((const float4*)bias)[q & (O_DIM / 4 - 1)];
        if (nphase == 2) {
            float4 w = ((const float4*)p1)[q];
            v.x += w.x; v.y += w.y; v.z += w.z; v.w += w.w;
        }
        v.x += b.x; v.y += b.y; v.z += b.z; v.w += b.w;
        ((float4*)out)[q] = v;
    }
}

extern "C" void kernel_launch(void* const* d_in, const int* in_sizes, int n_in,
                              void* d_out, int out_size, void* d_ws, size_t ws_size,
                              hipStream_t stream) {
    const float* x    = (const float*)d_in[0];
    const float* wts  = (const float*)d_in[1];
    const float* bias = (const float*)d_in[2];
    const float* pb   = (const float*)d_in[3];
    const float* pf   = (const float*)d_in[4];
    const float* pp   = (const float*)d_in[5];
    const float* un   = (const float*)d_in[6];
    float* out = (float*)d_out;

    unsigned short* wm = (unsigned short*)d_ws;              // 32 MB bf16 masked W
    unsigned short* xb = wm + (size_t)O_DIM * I_DIM;         // 4 MB bf16 x
    size_t p_off = ((size_t)O_DIM * I_DIM + (size_t)B_DIM * I_DIM) * 2;
    float* p1 = (float*)((char*)d_ws + p_off);               // 8 MB f32 partial

    int nphase = (ws_size >= p_off + (size_t)B_DIM * O_DIM * 4) ? 2 : 1;

    mask_kernel<<<2048, 256, 0, stream>>>(wts, pb, pf, pp, un, wm);
    cvt_kernel<<<512, 256, 0, stream>>>(x, xb);
    gemm_kernel<<<dim3(512 * nphase), 256, 0, stream>>>(xb, wm, out, p1, nphase);
    reduce_kernel<<<2048, 256, 0, stream>>>(out, p1, bias, nphase);
}